// Round 1
// 207.017 us; speedup vs baseline: 1.0205x; 1.0205x over previous
//
#include <hip/hip_runtime.h>

// YOLO loss, forward only. pred/target: (16384, 7, 7, 30) fp32, out: scalar fp32.
// S=7, B=2, CLS=20, N=30, LAMBDA_COORD=5, LAMBDA_NOOBJ=0.5, BATCH=16384.
// NOTE: reference conf_loc = arange(B)*B+4 = [4,6] (not [4,9]) — mirrored here.
//
// R2: coalesced DMA staging. R1 was limited by uncoalesced 120B-stride float2
// loads (each wave load = ~64 separate cache-line lookups -> TA/TCP address
// throughput bound at 22% HBM, 6.6% VALU). Now: global_load_lds dwordx4
// stages 128 cells/chunk (15360 B/array) linearly into LDS with 1024 B per
// instruction, double-buffered with counted s_waitcnt vmcnt(30).
// One wave per block, each wave stages ONLY its own cells -> zero barriers.
// LDS 60 KB/block -> 2 blocks/CU; latency hidden by 30 KB in-flight DMA per
// wave (>> ~9 KB BDP), not by occupancy.

#define TPB 64
#define CPC 128                       // cells per chunk (one wave's chunk)
#define CB  (CPC * 120)               // 15360 bytes per array per chunk
#define NCALLS (CB / 1024)            // 15 dwordx4 DMA instructions per array
#define R_TOTAL (16384 * 7 * 7)       // 802816 cells
#define NCHUNKS (R_TOTAL / CPC)       // 6272
#define GRID 512                      // 2 blocks/CU x 256 CU, grid-stride

__device__ __forceinline__ void gload_lds16(const void* g, void* l) {
    // lane i writes LDS[l + 16*i] <- global[g_i]; dest must be linear (m104).
    __builtin_amdgcn_global_load_lds(
        (const __attribute__((address_space(1))) void*)g,
        (__attribute__((address_space(3))) void*)l, 16, 0, 0);
}

__global__ __launch_bounds__(TPB) void yolo_loss_kernel(
    const float* __restrict__ pred, const float* __restrict__ target,
    float* __restrict__ out)
{
    __shared__ __align__(16) unsigned char smem[2][2 * CB];  // 61440 B

    const int lane = threadIdx.x;
    float sum = 0.0f;

    // prologue: stage chunk = blockIdx.x into buffer 0
    {
        const char* gp = (const char*)pred + (size_t)blockIdx.x * CB + lane * 16;
        const char* gt = (const char*)target + (size_t)blockIdx.x * CB + lane * 16;
        #pragma unroll
        for (int c = 0; c < NCALLS; c++) gload_lds16(gp + c * 1024, &smem[0][c * 1024]);
        #pragma unroll
        for (int c = 0; c < NCALLS; c++) gload_lds16(gt + c * 1024, &smem[0][CB + c * 1024]);
    }

    int buf = 0;
    for (size_t chunk = blockIdx.x; chunk < NCHUNKS; chunk += GRID) {
        const size_t next = chunk + GRID;
        if (next < NCHUNKS) {
            // issue next-chunk DMA into the other buffer (stays in flight
            // across the compute phase), then wait only for current chunk.
            const char* gp = (const char*)pred + next * CB + lane * 16;
            const char* gt = (const char*)target + next * CB + lane * 16;
            unsigned char* lb = smem[buf ^ 1];
            #pragma unroll
            for (int c = 0; c < NCALLS; c++) gload_lds16(gp + c * 1024, lb + c * 1024);
            #pragma unroll
            for (int c = 0; c < NCALLS; c++) gload_lds16(gt + c * 1024, lb + CB + c * 1024);
            asm volatile("s_waitcnt vmcnt(30)" ::: "memory");  // newest 30 = next chunk
        } else {
            asm volatile("s_waitcnt vmcnt(0)" ::: "memory");   // drain last chunk
        }

        const unsigned char* lb = smem[buf];
        #pragma unroll
        for (int half = 0; half < 2; half++) {
            const int cell = lane + half * 64;
            const float* pf = (const float*)(lb + cell * 120);
            const float* tf = (const float*)(lb + CB + cell * 120);

            const float t4 = tf[4];
            if (t4 == 0.0f) {
                // noobj: 0.5 * sum over conf_loc=[4,6] of (p-t)^2
                float d4 = pf[4] - t4;
                float d6 = pf[6] - tf[6];
                sum += 0.5f * (d4 * d4 + d6 * d6);
            } else if (t4 == 1.0f) {
                // target box -> xyxy (mirror reference float op order)
                float tx1 = tf[0] - tf[2] * 0.5f, ty1 = tf[1] - tf[3] * 0.5f;
                float tx2 = tf[0] + tf[2] * 0.5f, ty2 = tf[1] + tf[3] * 0.5f;
                float area2 = (tx2 - tx1) * (ty2 - ty1);

                // box 0
                float ax1 = pf[0] - pf[2] * 0.5f, ay1 = pf[1] - pf[3] * 0.5f;
                float ax2 = pf[0] + pf[2] * 0.5f, ay2 = pf[1] + pf[3] * 0.5f;
                float w0 = fmaxf(fminf(ax2, tx2) - fmaxf(ax1, tx1), 0.0f);
                float h0 = fmaxf(fminf(ay2, ty2) - fmaxf(ay1, ty1), 0.0f);
                float inter0 = w0 * h0;
                float uni0 = (ax2 - ax1) * (ay2 - ay1) + area2 - inter0;
                float iou0 = (uni0 > 0.0f) ? (inter0 / uni0) : 0.0f;

                // box 1
                float bx1 = pf[5] - pf[7] * 0.5f, by1 = pf[6] - pf[8] * 0.5f;
                float bx2 = pf[5] + pf[7] * 0.5f, by2 = pf[6] + pf[8] * 0.5f;
                float w1 = fmaxf(fminf(bx2, tx2) - fmaxf(bx1, tx1), 0.0f);
                float h1 = fmaxf(fminf(by2, ty2) - fmaxf(by1, ty1), 0.0f);
                float inter1 = w1 * h1;
                float uni1 = (bx2 - bx1) * (by2 - by1) + area2 - inter1;
                float iou1 = (uni1 > 0.0f) ? (inter1 / uni1) : 0.0f;

                // argmax over 2 -> first max index on ties
                bool j1 = (iou1 > iou0);
                float max_iou = fmaxf(iou0, iou1);
                float r0 = j1 ? pf[5] : pf[0];
                float r1 = j1 ? pf[6] : pf[1];
                float r2 = j1 ? pf[7] : pf[2];
                float r3 = j1 ? pf[8] : pf[3];
                float r4 = j1 ? pf[9] : pf[4];

                float dx = r0 - tf[0];
                float dy = r1 - tf[1];
                float sw = sqrtf(fmaxf(r2, 0.0f)) - sqrtf(fmaxf(tf[2], 0.0f));
                float sh = sqrtf(fmaxf(r3, 0.0f)) - sqrtf(fmaxf(tf[3], 0.0f));
                float coord = dx * dx + dy * dy + sw * sw + sh * sh;
                float dc = r4 - max_iou;

                float cls = 0.0f;
                #pragma unroll
                for (int k = 10; k < 30; k++) {
                    float d = pf[k] - tf[k];
                    cls += d * d;
                }
                sum += 5.0f * coord + dc * dc + cls;
            }
            // (t4 guaranteed in {0,1} by setup; other values contribute 0, matching ref)
        }
        buf ^= 1;
    }

    // wave-64 reduction, one atomic per block (512 atomics total)
    #pragma unroll
    for (int off = 32; off > 0; off >>= 1)
        sum += __shfl_down(sum, off, 64);
    if (lane == 0)
        atomicAdd(out, sum * (1.0f / 16384.0f));
}

extern "C" void kernel_launch(void* const* d_in, const int* in_sizes, int n_in,
                              void* d_out, int out_size, void* d_ws, size_t ws_size,
                              hipStream_t stream) {
    const float* pred = (const float*)d_in[0];
    const float* target = (const float*)d_in[1];
    float* out = (float*)d_out;
    // d_out is poisoned with 0xAA before every launch; we accumulate into it.
    hipMemsetAsync(out, 0, sizeof(float), stream);
    yolo_loss_kernel<<<GRID, TPB, 0, stream>>>(pred, target, out);
}

// Round 2
// 204.232 us; speedup vs baseline: 1.0344x; 1.0136x over previous
//
#include <hip/hip_runtime.h>

// YOLO loss, forward only. pred/target: (16384, 7, 7, 30) fp32, out: scalar fp32.
// S=7, B=2, CLS=20, N=30, LAMBDA_COORD=5, LAMBDA_NOOBJ=0.5, BATCH=16384.
// NOTE: reference conf_loc = arange(B)*B+4 = [4,6] (not [4,9]) — mirrored here.
//
// R3: reg-staged coalesced loads + LDS transpose. History:
//   R1 (register-direct, 120B-stride float2): 75 us — TA/TCP request-bound
//     (64 cache-line lookups per wave-load), 22% HBM.
//   R2 (global_load_lds DMA, 1 wave/block): 75 us — LDS-DMA delivers only
//     ~2.1 B/cyc/wave and only 2 waves/CU were queueing; 94% of each
//     iteration was vmcnt stall (VALUBusy 5.9%, occupancy 4.3%).
// R3 uses the m13-proven plain-load path: each 256-thread block stages one
// 256-cell tile (61440 B) with fully-coalesced global_load_dwordx4 into
// registers, ds_write_b128 a LINEAR LDS image, one barrier, then per-cell
// compute from LDS. 8 waves/CU x 16 loads in flight = ~120 KB/CU in-flight
// >> 9 KB bandwidth-delay product -> HBM-bound (~31 us ideal).
// Compute-phase LDS reads are 4-way bank-conflicted (cell stride 120 B);
// ~1.6x on ~300 cyc of LDS traffic, hidden under the ~6000-cyc memory phase.

#define TPB 256
#define CELLS 256                     // cells per block tile
#define CB 30720                      // bytes per array per tile (256*120)
#define GRID 3136                     // 802816 cells / 256

__global__ __launch_bounds__(TPB, 2) void yolo_loss_kernel(
    const float* __restrict__ pred, const float* __restrict__ target,
    float* __restrict__ out)
{
    // [0, CB): pred tile, [CB, 2*CB): target tile — linear byte image.
    __shared__ __align__(16) unsigned char smem[2 * CB];   // 61440 B
    __shared__ float red[TPB / 64];

    const int tid = threadIdx.x;
    const size_t base = (size_t)blockIdx.x * CB;           // byte offset per array

    // ---- stage: coalesced global -> regs -> linear LDS image ----
    // Per array: 7 x dwordx4 (lane stride 16 B) + 1 x dwordx2 (lane stride 8 B)
    // covers 7*4096 + 2048 = 30720 B. All lanes contiguous -> perfect coalescing.
    const char* gp = (const char*)pred + base;
    const char* gt = (const char*)target + base;
    float4 vp[7], vt[7];
    float2 wp, wt;
    #pragma unroll
    for (int i = 0; i < 7; i++) vp[i] = *(const float4*)(gp + i * 4096 + tid * 16);
    wp = *(const float2*)(gp + 28672 + tid * 8);
    #pragma unroll
    for (int i = 0; i < 7; i++) vt[i] = *(const float4*)(gt + i * 4096 + tid * 16);
    wt = *(const float2*)(gt + 28672 + tid * 8);

    #pragma unroll
    for (int i = 0; i < 7; i++) *(float4*)(smem + i * 4096 + tid * 16) = vp[i];
    *(float2*)(smem + 28672 + tid * 8) = wp;
    #pragma unroll
    for (int i = 0; i < 7; i++) *(float4*)(smem + CB + i * 4096 + tid * 16) = vt[i];
    *(float2*)(smem + CB + 28672 + tid * 8) = wt;
    __syncthreads();

    // ---- compute: thread tid owns cell tid ----
    const float* pf = (const float*)(smem) + tid * 30;
    const float* tf = (const float*)(smem + CB) + tid * 30;

    float sum = 0.0f;
    const float t4 = tf[4];
    if (t4 == 0.0f) {
        // noobj: 0.5 * sum over conf_loc=[4,6] of (p-t)^2
        float d4 = pf[4] - t4;
        float d6 = pf[6] - tf[6];
        sum = 0.5f * (d4 * d4 + d6 * d6);
    } else if (t4 == 1.0f) {
        // target box -> xyxy (mirror reference float op order)
        float tx1 = tf[0] - tf[2] * 0.5f, ty1 = tf[1] - tf[3] * 0.5f;
        float tx2 = tf[0] + tf[2] * 0.5f, ty2 = tf[1] + tf[3] * 0.5f;
        float area2 = (tx2 - tx1) * (ty2 - ty1);

        // box 0
        float ax1 = pf[0] - pf[2] * 0.5f, ay1 = pf[1] - pf[3] * 0.5f;
        float ax2 = pf[0] + pf[2] * 0.5f, ay2 = pf[1] + pf[3] * 0.5f;
        float w0 = fmaxf(fminf(ax2, tx2) - fmaxf(ax1, tx1), 0.0f);
        float h0 = fmaxf(fminf(ay2, ty2) - fmaxf(ay1, ty1), 0.0f);
        float inter0 = w0 * h0;
        float uni0 = (ax2 - ax1) * (ay2 - ay1) + area2 - inter0;
        float iou0 = (uni0 > 0.0f) ? (inter0 / uni0) : 0.0f;

        // box 1
        float bx1 = pf[5] - pf[7] * 0.5f, by1 = pf[6] - pf[8] * 0.5f;
        float bx2 = pf[5] + pf[7] * 0.5f, by2 = pf[6] + pf[8] * 0.5f;
        float w1 = fmaxf(fminf(bx2, tx2) - fmaxf(bx1, tx1), 0.0f);
        float h1 = fmaxf(fminf(by2, ty2) - fmaxf(by1, ty1), 0.0f);
        float inter1 = w1 * h1;
        float uni1 = (bx2 - bx1) * (by2 - by1) + area2 - inter1;
        float iou1 = (uni1 > 0.0f) ? (inter1 / uni1) : 0.0f;

        // argmax over 2 -> first max index on ties
        bool j1 = (iou1 > iou0);
        float max_iou = fmaxf(iou0, iou1);
        // responsible box via per-element select (no dynamic indexing)
        float r0 = j1 ? pf[5] : pf[0];
        float r1 = j1 ? pf[6] : pf[1];
        float r2 = j1 ? pf[7] : pf[2];
        float r3 = j1 ? pf[8] : pf[3];
        float r4 = j1 ? pf[9] : pf[4];

        float dx = r0 - tf[0];
        float dy = r1 - tf[1];
        float sw = sqrtf(fmaxf(r2, 0.0f)) - sqrtf(fmaxf(tf[2], 0.0f));
        float sh = sqrtf(fmaxf(r3, 0.0f)) - sqrtf(fmaxf(tf[3], 0.0f));
        float coord = dx * dx + dy * dy + sw * sw + sh * sh;
        float dc = r4 - max_iou;

        float cls = 0.0f;
        #pragma unroll
        for (int k = 10; k < 30; k++) {
            float d = pf[k] - tf[k];
            cls += d * d;
        }
        sum = 5.0f * coord + dc * dc + cls;
    }
    // (t4 guaranteed in {0,1} by setup; other values contribute 0, matching ref)

    // ---- reduce: wave-64 shfl, then 4 partials via LDS, one atomic/block ----
    #pragma unroll
    for (int off = 32; off > 0; off >>= 1)
        sum += __shfl_down(sum, off, 64);
    if ((tid & 63) == 0) red[tid >> 6] = sum;
    __syncthreads();
    if (tid == 0) {
        float s = red[0] + red[1] + red[2] + red[3];
        atomicAdd(out, s * (1.0f / 16384.0f));
    }
}

extern "C" void kernel_launch(void* const* d_in, const int* in_sizes, int n_in,
                              void* d_out, int out_size, void* d_ws, size_t ws_size,
                              hipStream_t stream) {
    const float* pred = (const float*)d_in[0];
    const float* target = (const float*)d_in[1];
    float* out = (float*)d_out;
    // d_out is poisoned with 0xAA before every launch; we accumulate into it.
    hipMemsetAsync(out, 0, sizeof(float), stream);
    yolo_loss_kernel<<<GRID, TPB, 0, stream>>>(pred, target, out);
}